// Round 1
// baseline (5149.179 us; speedup 1.0000x reference)
//
#include <hip/hip_runtime.h>
#include <math.h>

#define T_STEPS 256
#define BATCH   4096
#define HID     64
#define MW      128
#define DOUT    8
#define RPB     16      // rows (batch elems) per block
#define NTH     256
#define AP      20      // padded inner dim for transposed LDS tiles (16B-aligned rows, conflict-free)

__device__ __forceinline__ float lipswish(float x) {
    return 0.909f * x / (1.0f + expf(-x));
}

__global__ __launch_bounds__(NTH)
void sde_kernel(const float* __restrict__ ts,
                const float* __restrict__ dW,
                const float* __restrict__ dW0, const float* __restrict__ db0,
                const float* __restrict__ dW1, const float* __restrict__ db1,
                const float* __restrict__ dWo, const float* __restrict__ dbo,
                const float* __restrict__ gW0, const float* __restrict__ gb0,
                const float* __restrict__ gW1, const float* __restrict__ gb1,
                const float* __restrict__ gWo, const float* __restrict__ gbo,
                const float* __restrict__ rW,  const float* __restrict__ rb,
                float* __restrict__ out)
{
    // Transposed activation tiles: [feature][row], row-dim padded to AP=20
    __shared__ __align__(16) float aT[65 * AP];      // MLP input (t, x) : 65 x R
    __shared__ __align__(16) float h1d[MW * AP];     // drift layer-1 out
    __shared__ __align__(16) float h1g[MW * AP];     // diff  layer-1 out
    __shared__ __align__(16) float h2d[MW * AP];     // drift layer-2 out (reused as z-scratch)
    __shared__ __align__(16) float h2g[MW * AP];     // diff  layer-2 out
    __shared__ float fbuf[RPB * HID];                // f_n  (drift MLP out)
    __shared__ float gbuf[RPB * HID];                // g_n  (diff MLP out)
    __shared__ float rWs[HID * DOUT];
    __shared__ float rbs[DOUT];

    const int tid = threadIdx.x;
    const int rowbase = blockIdx.x * RPB;

    for (int i = tid; i < HID * DOUT; i += NTH) rWs[i] = rW[i];
    if (tid < DOUT) rbs[tid] = rb[tid];

    const float dt   = ts[1] - ts[0];
    const float sqdt = sqrtf(dt);

    // update-phase mapping: lane dim + 4 rows per thread
    const int ud  = tid & 63;
    const int urb = tid >> 6;          // rows urb + 4*i

    // layer-1/2 mapping: neuron j, 8 rows per thread
    const int j1  = tid & 127;
    const int r01 = (tid >> 7) * 8;
    // layer-3 mapping: neuron j (64), 4 rows per thread
    const int j3  = tid & 63;
    const int r03 = (tid >> 6) * 4;

    float z[4], zh[4], fold[4], gold[4], dwr[4];
    #pragma unroll
    for (int i = 0; i < 4; ++i) { z[i] = 1.0f; zh[i] = 1.0f; }

    for (int n = 0; n < T_STEPS; ++n) {
        const float tn = ts[n];

        if (n == 0) {
            // x0 = ones, t = ts[0]
            #pragma unroll
            for (int i = 0; i < 4; ++i) {
                const int r = urb + 4 * i;
                aT[(1 + ud) * AP + r] = 1.0f;
                if (ud == 0) aT[r] = tn;
            }
        } else {
            // zhat_{n} = 2 z - zhat + f dt + g dw   ; build MLP input (ts[n], zhat_n)
            const float* dWn = dW + (size_t)(n - 1) * (BATCH * HID) + (size_t)rowbase * HID;
            #pragma unroll
            for (int i = 0; i < 4; ++i) {
                const int r  = urb + 4 * i;
                const float fo = fbuf[r * HID + ud];
                const float go = gbuf[r * HID + ud];
                const float dw = dWn[r * HID + ud] * sqdt;
                const float znew = 2.0f * z[i] - zh[i] + fo * dt + go * dw;
                zh[i]   = znew;
                fold[i] = fo; gold[i] = go; dwr[i] = dw;
                aT[(1 + ud) * AP + r] = znew;
                if (ud == 0) aT[r] = tn;
            }
        }
        __syncthreads();

        // ---------- Layer 1 (fused drift+diff; shared input aT) ----------
        {
            float ad[8], ag[8];
            const float bd = db0[j1], bg = gb0[j1];
            #pragma unroll
            for (int i = 0; i < 8; ++i) { ad[i] = bd; ag[i] = bg; }
            #pragma unroll 5
            for (int k = 0; k < 65; ++k) {
                const float wd = dW0[k * MW + j1];
                const float wg = gW0[k * MW + j1];
                const float4 a0 = *reinterpret_cast<const float4*>(&aT[k * AP + r01]);
                const float4 a1 = *reinterpret_cast<const float4*>(&aT[k * AP + r01 + 4]);
                const float av[8] = {a0.x, a0.y, a0.z, a0.w, a1.x, a1.y, a1.z, a1.w};
                #pragma unroll
                for (int i = 0; i < 8; ++i) {
                    ad[i] = fmaf(av[i], wd, ad[i]);
                    ag[i] = fmaf(av[i], wg, ag[i]);
                }
            }
            float od[8], og[8];
            #pragma unroll
            for (int i = 0; i < 8; ++i) { od[i] = lipswish(ad[i]); og[i] = lipswish(ag[i]); }
            *reinterpret_cast<float4*>(&h1d[j1 * AP + r01])     = make_float4(od[0], od[1], od[2], od[3]);
            *reinterpret_cast<float4*>(&h1d[j1 * AP + r01 + 4]) = make_float4(od[4], od[5], od[6], od[7]);
            *reinterpret_cast<float4*>(&h1g[j1 * AP + r01])     = make_float4(og[0], og[1], og[2], og[3]);
            *reinterpret_cast<float4*>(&h1g[j1 * AP + r01 + 4]) = make_float4(og[4], og[5], og[6], og[7]);
        }
        __syncthreads();

        // ---------- Layer 2 (drift and diff, separate inputs) ----------
        {
            float ad[8], ag[8];
            const float bd = db1[j1], bg = gb1[j1];
            #pragma unroll
            for (int i = 0; i < 8; ++i) { ad[i] = bd; ag[i] = bg; }
            #pragma unroll 4
            for (int k = 0; k < MW; ++k) {
                const float wd = dW1[k * MW + j1];
                const float wg = gW1[k * MW + j1];
                const float4 d0 = *reinterpret_cast<const float4*>(&h1d[k * AP + r01]);
                const float4 d1 = *reinterpret_cast<const float4*>(&h1d[k * AP + r01 + 4]);
                const float4 g0 = *reinterpret_cast<const float4*>(&h1g[k * AP + r01]);
                const float4 g1 = *reinterpret_cast<const float4*>(&h1g[k * AP + r01 + 4]);
                const float dv[8] = {d0.x, d0.y, d0.z, d0.w, d1.x, d1.y, d1.z, d1.w};
                const float gv[8] = {g0.x, g0.y, g0.z, g0.w, g1.x, g1.y, g1.z, g1.w};
                #pragma unroll
                for (int i = 0; i < 8; ++i) {
                    ad[i] = fmaf(dv[i], wd, ad[i]);
                    ag[i] = fmaf(gv[i], wg, ag[i]);
                }
            }
            float od[8], og[8];
            #pragma unroll
            for (int i = 0; i < 8; ++i) { od[i] = lipswish(ad[i]); og[i] = lipswish(ag[i]); }
            *reinterpret_cast<float4*>(&h2d[j1 * AP + r01])     = make_float4(od[0], od[1], od[2], od[3]);
            *reinterpret_cast<float4*>(&h2d[j1 * AP + r01 + 4]) = make_float4(od[4], od[5], od[6], od[7]);
            *reinterpret_cast<float4*>(&h2g[j1 * AP + r01])     = make_float4(og[0], og[1], og[2], og[3]);
            *reinterpret_cast<float4*>(&h2g[j1 * AP + r01 + 4]) = make_float4(og[4], og[5], og[6], og[7]);
        }
        __syncthreads();

        // ---------- Layer 3 (tanh output -> fbuf/gbuf) ----------
        {
            float ad[4], ag[4];
            const float bd = dbo[j3], bg = gbo[j3];
            #pragma unroll
            for (int i = 0; i < 4; ++i) { ad[i] = bd; ag[i] = bg; }
            #pragma unroll 4
            for (int k = 0; k < MW; ++k) {
                const float wd = dWo[k * HID + j3];
                const float wg = gWo[k * HID + j3];
                const float4 xd = *reinterpret_cast<const float4*>(&h2d[k * AP + r03]);
                const float4 xg = *reinterpret_cast<const float4*>(&h2g[k * AP + r03]);
                const float dv[4] = {xd.x, xd.y, xd.z, xd.w};
                const float gv[4] = {xg.x, xg.y, xg.z, xg.w};
                #pragma unroll
                for (int i = 0; i < 4; ++i) {
                    ad[i] = fmaf(dv[i], wd, ad[i]);
                    ag[i] = fmaf(gv[i], wg, ag[i]);
                }
            }
            #pragma unroll
            for (int i = 0; i < 4; ++i) {
                fbuf[(r03 + i) * HID + j3] = tanhf(ad[i]);   // TSCALE = 1
                gbuf[(r03 + i) * HID + j3] = tanhf(ag[i]);
            }
        }
        __syncthreads();

        // ---------- z update + stash z for readout ----------
        if (n > 0) {
            #pragma unroll
            for (int i = 0; i < 4; ++i) {
                const int r = urb + 4 * i;
                const float fn = fbuf[r * HID + ud];
                const float gn = gbuf[r * HID + ud];
                z[i] += 0.5f * (fold[i] + fn) * dt + 0.5f * (gold[i] + gn) * dwr[i];
            }
        }
        #pragma unroll
        for (int i = 0; i < 4; ++i) {
            const int r = urb + 4 * i;
            h2d[r * 68 + ud] = z[i];    // zscratch (h2d free after layer 3), stride 68 = conflict-free
        }
        __syncthreads();

        // ---------- readout: out[b][n] = [ts[n], z_n @ rW + rb] ----------
        if (tid < RPB * DOUT) {
            const int r  = tid >> 3;
            const int dd = tid & 7;
            float acc = rbs[dd];
            #pragma unroll 8
            for (int k = 0; k < HID; ++k)
                acc = fmaf(h2d[r * 68 + k], rWs[k * DOUT + dd], acc);
            float* op = out + (size_t)(rowbase + r) * (T_STEPS * (DOUT + 1))
                            + (size_t)n * (DOUT + 1);
            op[1 + dd] = acc;
            if (dd == 0) op[0] = tn;
        }
        __syncthreads();
    }
}

extern "C" void kernel_launch(void* const* d_in, const int* in_sizes, int n_in,
                              void* d_out, int out_size, void* d_ws, size_t ws_size,
                              hipStream_t stream) {
    const float* ts  = (const float*)d_in[0];
    // d_in[1] = batch_size (int, fixed 4096) - unused
    const float* dW  = (const float*)d_in[2];
    const float* dW0 = (const float*)d_in[3];
    const float* db0 = (const float*)d_in[4];
    const float* dW1 = (const float*)d_in[5];
    const float* db1 = (const float*)d_in[6];
    const float* dWo = (const float*)d_in[7];
    const float* dbo = (const float*)d_in[8];
    const float* gW0 = (const float*)d_in[9];
    const float* gb0 = (const float*)d_in[10];
    const float* gW1 = (const float*)d_in[11];
    const float* gb1 = (const float*)d_in[12];
    const float* gWo = (const float*)d_in[13];
    const float* gbo = (const float*)d_in[14];
    const float* rW  = (const float*)d_in[15];
    const float* rb  = (const float*)d_in[16];
    float* out = (float*)d_out;

    sde_kernel<<<dim3(BATCH / RPB), dim3(NTH), 0, stream>>>(
        ts, dW, dW0, db0, dW1, db1, dWo, dbo,
        gW0, gb0, gW1, gb1, gWo, gbo, rW, rb, out);
}